// Round 10
// baseline (248.535 us; speedup 1.0000x reference)
//
#include <hip/hip_runtime.h>
#include <hip/hip_bf16.h>

#define D_MODEL 1024
#define N_HEAD  16
#define D_K     64
#define MAX_LEN 1000
#define B_      4
#define S_      1000
#define S_PAD   1024
#define M_PAD   (B_ * S_PAD)       // 4096
#define M_REAL  (B_ * S_)          // 4000
#define LN_EPS  1e-5f
#define SCALE_L2E 0.1803368801111204f   // 0.125 * log2(e)
#define REL_ROWS (2*MAX_LEN-1)     // 1999

typedef __attribute__((ext_vector_type(8))) short short8;
typedef __attribute__((ext_vector_type(4))) float f32x4;

__device__ __forceinline__ unsigned short f2b(float f) {
    unsigned u = __builtin_bit_cast(unsigned, f);
    u = (u + 0x7FFFu + ((u >> 16) & 1u)) >> 16;
    return (unsigned short)u;
}

__device__ __forceinline__ unsigned short f2b_trunc(float f) {
    return (unsigned short)(__builtin_bit_cast(unsigned, f) >> 16);
}

__device__ __forceinline__ float b2f(unsigned short u) {
    return __builtin_bit_cast(float, (unsigned)u << 16);
}

__device__ __forceinline__ f32x4 mfma16(short8 a, short8 b, f32x4 c) {
    return __builtin_amdgcn_mfma_f32_16x16x32_bf16(a, b, c, 0, 0, 0);
}

__device__ __forceinline__ void gload_lds16(const void* g, void* l) {
    __builtin_amdgcn_global_load_lds(
        (const __attribute__((address_space(1))) unsigned int*)g,
        (__attribute__((address_space(3))) unsigned int*)l, 16, 0, 0);
}

// ---------------- merged fp32 -> bf16 convert (5 tensors) ----------------
__global__ void cvt_all(const float* __restrict__ s0, const float* __restrict__ s1,
                        const float* __restrict__ s2, const float* __restrict__ s3,
                        const float* __restrict__ s4,
                        unsigned short* __restrict__ d0, unsigned short* __restrict__ d1,
                        unsigned short* __restrict__ d2, unsigned short* __restrict__ d3,
                        unsigned short* __restrict__ d4) {
    int y = blockIdx.y;
    const float* in; unsigned short* out; int n4;
    switch (y) {
        case 0: in = s0; out = d0; n4 = 262144; break;
        case 1: in = s1; out = d1; n4 = 262144; break;
        case 2: in = s2; out = d2; n4 = 262144; break;
        case 3: in = s3; out = d3; n4 = 262144; break;
        default: in = s4; out = d4; n4 = REL_ROWS * D_K / 4; break;
    }
    int i = blockIdx.x * blockDim.x + threadIdx.x;
    if (i >= n4) return;
    float4 v = ((const float4*)in)[i];
    ushort4 o;
    o.x = f2b(v.x); o.y = f2b(v.y); o.z = f2b(v.z); o.w = f2b(v.w);
    ((ushort4*)out)[i] = o;
}

// ---------------- merged LayerNorm x3 -> bf16, padded rows zeroed ----------------
__global__ void ln_all(const float* __restrict__ xq, const float* __restrict__ xk,
                       const float* __restrict__ xv, const float* __restrict__ g,
                       const float* __restrict__ beta,
                       unsigned short* __restrict__ yq, unsigned short* __restrict__ yk,
                       unsigned short* __restrict__ yv) {
    int which = blockIdx.y;
    const float* x = which == 0 ? xq : which == 1 ? xk : xv;
    unsigned short* y = which == 0 ? yq : which == 1 ? yk : yv;

    int r = blockIdx.x;            // padded row index
    int b = r >> 10, i = r & 1023;
    unsigned short* yr = y + (size_t)r * D_MODEL;
    int tid = threadIdx.x;
    if (i >= S_) {
#pragma unroll
        for (int l = 0; l < 4; ++l) yr[tid + l * 256] = 0;
        return;
    }
    const float* xr = x + ((size_t)b * S_ + i) * D_MODEL;
    float v[4];
    float s = 0.f, sq = 0.f;
#pragma unroll
    for (int l = 0; l < 4; ++l) {
        v[l] = xr[tid + l * 256];
        s += v[l];
        sq += v[l] * v[l];
    }
#pragma unroll
    for (int o = 32; o > 0; o >>= 1) {
        s += __shfl_down(s, o, 64);
        sq += __shfl_down(sq, o, 64);
    }
    __shared__ float rs[4], rq[4];
    if ((tid & 63) == 0) { rs[tid >> 6] = s; rq[tid >> 6] = sq; }
    __syncthreads();
    if (tid == 0) {
        rs[0] = rs[0] + rs[1] + rs[2] + rs[3];
        rq[0] = rq[0] + rq[1] + rq[2] + rq[3];
    }
    __syncthreads();
    float mu = rs[0] * (1.0f / D_MODEL);
    float var = rq[0] * (1.0f / D_MODEL) - mu * mu;
    float rstd = rsqrtf(var + LN_EPS);
#pragma unroll
    for (int l = 0; l < 4; ++l) {
        int c = tid + l * 256;
        yr[c] = f2b((v[l] - mu) * rstd * g[c] + beta[c]);
    }
}

// ---------------- GEMM core ----------------
// MODE 0: head layout [b,h,i,d]; MODE 1: transposed head [b,h,d,i]; MODE 2: fp32 +resid
template<int MODE>
__device__ __forceinline__ void gemm_body(
        const unsigned short* __restrict__ X, const unsigned short* __restrict__ W,
        const float* __restrict__ bias, const float* __restrict__ resid,
        unsigned short* __restrict__ Yb, float* __restrict__ Yf,
        unsigned short* As, unsigned short* Bs, int row0, int col0) {
    int tid = threadIdx.x;
    int lane = tid & 63, w = tid >> 6;
    int wr = w >> 1, wc = w & 1;
    int fr = lane & 15, fk = (lane >> 4) * 8;

    f32x4 acc[4][4];
#pragma unroll
    for (int fm = 0; fm < 4; ++fm)
#pragma unroll
        for (int fn = 0; fn < 4; ++fn) acc[fm][fn] = (f32x4)0.f;

    int c0 = (w * 2 + 0) * 64 + lane;
    int c1 = (w * 2 + 1) * 64 + lane;
    const unsigned short* xs0 = X + (size_t)(row0 + (c0 >> 2)) * 1024 + (c0 & 3) * 8;
    const unsigned short* xs1 = X + (size_t)(row0 + (c1 >> 2)) * 1024 + (c1 & 3) * 8;
    const unsigned short* ws0 = W + (size_t)(col0 + (c0 >> 2)) * 1024 + (c0 & 3) * 8;
    const unsigned short* ws1 = W + (size_t)(col0 + (c1 >> 2)) * 1024 + (c1 & 3) * 8;
    unsigned short* ad0 = As + (w * 2 + 0) * 512;
    unsigned short* ad1 = As + (w * 2 + 1) * 512;
    unsigned short* bd0 = Bs + (w * 2 + 0) * 512;
    unsigned short* bd1 = Bs + (w * 2 + 1) * 512;

    for (int k0 = 0; k0 < 1024; k0 += 32) {
        gload_lds16(xs0 + k0, ad0);
        gload_lds16(xs1 + k0, ad1);
        gload_lds16(ws0 + k0, bd0);
        gload_lds16(ws1 + k0, bd1);
        __syncthreads();
        short8 a[4], b[4];
#pragma unroll
        for (int fm = 0; fm < 4; ++fm)
            a[fm] = *(const short8*)(As + (wr * 64 + fm * 16 + fr) * 32 + fk);
#pragma unroll
        for (int fn = 0; fn < 4; ++fn)
            b[fn] = *(const short8*)(Bs + (wc * 64 + fn * 16 + fr) * 32 + fk);
#pragma unroll
        for (int fm = 0; fm < 4; ++fm)
#pragma unroll
            for (int fn = 0; fn < 4; ++fn)
                acc[fm][fn] = mfma16(a[fm], b[fn], acc[fm][fn]);
        __syncthreads();
    }

#pragma unroll
    for (int fm = 0; fm < 4; ++fm) {
#pragma unroll
        for (int fn = 0; fn < 4; ++fn) {
            int cg = col0 + wc * 64 + fn * 16 + fr;
            float bv = bias[cg];
#pragma unroll
            for (int r = 0; r < 4; ++r) {
                int rg = row0 + wr * 64 + fm * 16 + (lane >> 4) * 4 + r;
                float val = acc[fm][fn][r] + bv;
                int b_ = rg >> 10, i = rg & 1023;
                if (MODE == 0) {
                    int h = cg >> 6, d = cg & 63;
                    Yb[(((size_t)(b_ * N_HEAD + h)) * S_PAD + i) * D_K + d] = f2b(val);
                } else if (MODE == 1) {
                    int h = cg >> 6, d = cg & 63;
                    Yb[(((size_t)(b_ * N_HEAD + h)) * D_K + d) * S_PAD + i] = f2b(val);
                } else {
                    if (i < S_) {
                        size_t orow = (size_t)b_ * S_ + i;
                        Yf[orow * 1024 + cg] = val + resid[orow * 1024 + cg];
                    }
                }
            }
        }
    }
}

// merged Q/K/V projections: grid (8, 32, 3)
__global__ __launch_bounds__(256) void gemm_qkv(
        const unsigned short* __restrict__ qn, const unsigned short* __restrict__ kn,
        const unsigned short* __restrict__ vn,
        const unsigned short* __restrict__ wqb, const unsigned short* __restrict__ wkb,
        const unsigned short* __restrict__ wvb,
        const float* __restrict__ bq, const float* __restrict__ bk,
        const float* __restrict__ bv,
        unsigned short* __restrict__ qh, unsigned short* __restrict__ kh,
        unsigned short* __restrict__ vt) {
    __shared__ __align__(16) unsigned short As[128 * 32];
    __shared__ __align__(16) unsigned short Bs[128 * 32];
    int z = blockIdx.z;
    int row0 = blockIdx.y * 128, col0 = blockIdx.x * 128;
    if (z == 0)
        gemm_body<0>(qn, wqb, bq, nullptr, qh, nullptr, As, Bs, row0, col0);
    else if (z == 1)
        gemm_body<0>(kn, wkb, bk, nullptr, kh, nullptr, As, Bs, row0, col0);
    else
        gemm_body<1>(vn, wvb, bv, nullptr, vt, nullptr, As, Bs, row0, col0);
}

// final output projection + residual
__global__ __launch_bounds__(256) void gemm_out(
        const unsigned short* __restrict__ X, const unsigned short* __restrict__ W,
        const float* __restrict__ bias, const float* __restrict__ resid,
        float* __restrict__ Yf) {
    __shared__ __align__(16) unsigned short As[128 * 32];
    __shared__ __align__(16) unsigned short Bs[128 * 32];
    gemm_body<2>(X, W, bias, resid, nullptr, Yf, As, Bs, blockIdx.y * 128, blockIdx.x * 128);
}

// ---------------- Flash attention: 8-wave blocks, dbuf K/V, 1 slab/wave ----------------
// 512 blocks x 512 threads. Block = one bh, 8 slabs (wave w owns slab w of its group).
// K/V staged to dbuf LDS (1 K-load + 1 V-load per wave per iter); one barrier per iter.
#define QRW 84    // QR scratch stride (79 used)
#define PW  72    // P scratch stride (64 used), same buffer as QR
__global__ __launch_bounds__(512) void attn_mfma(
        const unsigned short* __restrict__ qh, const unsigned short* __restrict__ kh,
        const unsigned short* __restrict__ vt, const unsigned short* __restrict__ relb,
        unsigned short* __restrict__ aout) {
    __shared__ __align__(16) unsigned short Ks[2][64 * 64];   // 16 KB
    __shared__ __align__(16) unsigned short Vs[2][64 * 64];   // 16 KB
    __shared__ __align__(16) unsigned short QP[8][16 * QRW];  // 21 KB

    int tid = threadIdx.x, lane = tid & 63, w = tid >> 6;     // w in 0..7
    int bid = blockIdx.x;                      // 512 blocks
    int swz = (bid & 7) * 64 + (bid >> 3);     // XCD-chunked, bijective (512 = 8*64)
    int bh = swz >> 3;                         // uniform across block
    int i0 = (((swz & 7) * 8) + w) * 16;       // this wave's slab
    int fr = lane & 15, fk8 = (lane >> 4) * 8, rgrp = (lane >> 4) * 4;
    int rsw = (fr & 7) << 3;                   // read-side XOR (ushort units)

    const unsigned short* kbase = kh + (size_t)bh * S_PAD * D_K;   // [i][d]
    const unsigned short* vtbase = vt + (size_t)bh * D_K * S_PAD;  // [d][i]

    const unsigned short* qp_g = qh + ((size_t)bh * S_PAD + i0 + fr) * D_K + fk8;
    short8 aq0 = *(const short8*)(qp_g);
    short8 aq1 = *(const short8*)(qp_g + 32);

    f32x4 accO[4];
    float mrun[4], lrun[4];
#pragma unroll
    for (int fd = 0; fd < 4; ++fd) accO[fd] = (f32x4)0.f;
#pragma unroll
    for (int r = 0; r < 4; ++r) { mrun[r] = -3e38f; lrun[r] = 0.f; }

    unsigned short* qp = QP[w];
    int row_in = lane >> 3, slot = lane & 7;

    auto stage = [&](int buf, int it2) {
        int j0s = it2 * 64;
        int r = w * 8 + row_in;
        gload_lds16(kbase + (size_t)(j0s + r) * 64 + (slot ^ row_in) * 8,
                    &Ks[buf][w * 512]);
        gload_lds16(vtbase + (size_t)r * S_PAD + j0s + (slot ^ row_in) * 8,
                    &Vs[buf][w * 512]);
    };

    stage(0, 0);
    __syncthreads();   // tile 0 landed

    for (int it = 0; it < 16; ++it) {
        int cur = it & 1, j0 = it * 64;
        bool mask_needed = (j0 + 63 >= S_);

        // rel fragments issued first (counted ahead of stage loads)
        short8 rl[5][2];
        int ub = i0 - j0 + (S_ - D_K);
#pragma unroll
        for (int fu = 0; fu < 5; ++fu) {
            int u = ub + fu * 16 + fr;
            u = u < 0 ? 0 : (u > REL_ROWS - 1 ? REL_ROWS - 1 : u);
            const unsigned short* rp = relb + (size_t)u * D_K + fk8;
            rl[fu][0] = *(const short8*)(rp);
            rl[fu][1] = *(const short8*)(rp + 32);
        }
        __builtin_amdgcn_sched_barrier(0);

        if (it < 15) stage(cur ^ 1, it + 1);   // prefetch next tile

        const unsigned short* Kc = Ks[cur];
        const unsigned short* Vc = Vs[cur];

        // ---- QK^T from LDS ----
        f32x4 accS[4];
#pragma unroll
        for (int fj = 0; fj < 4; ++fj) accS[fj] = (f32x4)0.f;
#pragma unroll
        for (int fj = 0; fj < 4; ++fj) {
            int kb = (fj * 16 + fr) * 64 + fk8;
            accS[fj] = mfma16(aq0, *(const short8*)(Kc + (kb ^ rsw)), accS[fj]);
            accS[fj] = mfma16(aq1, *(const short8*)(Kc + ((kb + 32) ^ rsw)), accS[fj]);
        }

        // ---- Q @ relband^T; spill (truncated bf16) for diagonal gather ----
#pragma unroll
        for (int fu = 0; fu < 5; ++fu) {
            f32x4 qr = (f32x4)0.f;
            qr = mfma16(aq0, rl[fu][0], qr);
            qr = mfma16(aq1, rl[fu][1], qr);
#pragma unroll
            for (int r = 0; r < 4; ++r)
                qp[(rgrp + r) * QRW + fu * 16 + fr] = f2b_trunc(qr[r]);
        }

        // ---- assemble scores ----
        float sc[4][4];
#pragma unroll
        for (int fj = 0; fj < 4; ++fj) {
            int j_loc = fj * 16 + fr;
#pragma unroll
            for (int r = 0; r < 4; ++r) {
                int col = rgrp + r - j_loc + 63;   // in [0,78]
                sc[fj][r] = (accS[fj][r] + b2f(qp[(rgrp + r) * QRW + col])) * SCALE_L2E;
            }
        }
        if (mask_needed) {
#pragma unroll
            for (int fj = 0; fj < 4; ++fj) {
                int j_loc = fj * 16 + fr;
                if (j0 + j_loc >= S_) {
#pragma unroll
                    for (int r = 0; r < 4; ++r) sc[fj][r] = -3e38f;
                }
            }
        }

        // ---- row max ----
        float pm[4];
#pragma unroll
        for (int r = 0; r < 4; ++r)
            pm[r] = fmaxf(fmaxf(sc[0][r], sc[1][r]), fmaxf(sc[2][r], sc[3][r]));
#pragma unroll
        for (int mask = 1; mask <= 8; mask <<= 1)
#pragma unroll
            for (int r = 0; r < 4; ++r)
                pm[r] = fmaxf(pm[r], __shfl_xor(pm[r], mask, 64));

        // ---- defer-max: rescale only when max grew by > 8 (log2 units) ----
        float dmax = fmaxf(fmaxf(pm[0] - mrun[0], pm[1] - mrun[1]),
                           fmaxf(pm[2] - mrun[2], pm[3] - mrun[3]));
        if (!__all(dmax <= 8.0f)) {
#pragma unroll
            for (int r = 0; r < 4; ++r) {
                float mn = fmaxf(mrun[r], pm[r]);
                float scl = __builtin_amdgcn_exp2f(mrun[r] - mn);
                mrun[r] = mn;
                lrun[r] *= scl;
#pragma unroll
                for (int fd = 0; fd < 4; ++fd) accO[fd][r] *= scl;
            }
        }

        // ---- exp (base-2) + truncated bf16 P store ----
        float rsum[4];
#pragma unroll
        for (int r = 0; r < 4; ++r) rsum[r] = 0.f;
#pragma unroll
        for (int fj = 0; fj < 4; ++fj) {
#pragma unroll
            for (int r = 0; r < 4; ++r) {
                float p = __builtin_amdgcn_exp2f(sc[fj][r] - mrun[r]);
                rsum[r] += p;
                qp[(rgrp + r) * PW + fj * 16 + fr] = f2b_trunc(p);
            }
        }
#pragma unroll
        for (int mask = 1; mask <= 8; mask <<= 1)
#pragma unroll
            for (int r = 0; r < 4; ++r)
                rsum[r] += __shfl_xor(rsum[r], mask, 64);
#pragma unroll
        for (int r = 0; r < 4; ++r) lrun[r] += rsum[r];

        // ---- PV from LDS ----
        short8 ap0 = *(const short8*)(qp + fr * PW + fk8);
        short8 ap1 = *(const short8*)(qp + fr * PW + 32 + fk8);
#pragma unroll
        for (int fd = 0; fd < 4; ++fd) {
            int vb = (fd * 16 + fr) * 64 + fk8;
            accO[fd] = mfma16(ap0, *(const short8*)(Vc + (vb ^ rsw)), accO[fd]);
            accO[fd] = mfma16(ap1, *(const short8*)(Vc + ((vb + 32) ^ rsw)), accO[fd]);
        }

        __syncthreads();   // next tile landed; all waves done with Ks/Vs[cur]
    }

    // ---- normalize + store ----
    int b_ = bh >> 4, h = bh & 15;
#pragma unroll
    for (int r = 0; r < 4; ++r) {
        float inv = 1.0f / lrun[r];
        int m = b_ * S_PAD + i0 + rgrp + r;
#pragma unroll
        for (int fd = 0; fd < 4; ++fd) {
            int c = h * D_K + fd * 16 + fr;
            aout[(size_t)m * D_MODEL + c] = f2b(accO[fd][r] * inv);
        }
    }
}

extern "C" void kernel_launch(void* const* d_in, const int* in_sizes, int n_in,
                              void* d_out, int out_size, void* d_ws, size_t ws_size,
                              hipStream_t stream) {
    const float* q    = (const float*)d_in[0];
    const float* k    = (const float*)d_in[1];
    const float* v    = (const float*)d_in[2];
    const float* ln_g = (const float*)d_in[3];
    const float* ln_b = (const float*)d_in[4];
    const float* wq   = (const float*)d_in[5];
    const float* bq   = (const float*)d_in[6];
    const float* wk   = (const float*)d_in[7];
    const float* bk   = (const float*)d_in[8];
    const float* wv   = (const float*)d_in[9];
    const float* bv   = (const float*)d_in[10];
    const float* wo   = (const float*)d_in[11];
    const float* bo   = (const float*)d_in[12];
    const float* rel  = (const float*)d_in[13];
    float* out = (float*)d_out;

    const size_t TSZ = (size_t)M_PAD * D_MODEL;     // 4,194,304 ushorts
    unsigned short* ws   = (unsigned short*)d_ws;
    unsigned short* qn   = ws;
    unsigned short* kn   = qn + TSZ;
    unsigned short* vn   = kn + TSZ;
    unsigned short* qh   = vn + TSZ;
    unsigned short* kh   = qh + TSZ;
    unsigned short* vt   = kh + TSZ;
    unsigned short* aout = vt + TSZ;
    unsigned short* wqb  = aout + TSZ;
    unsigned short* wkb  = wqb + 1024 * 1024;
    unsigned short* wvb  = wkb + 1024 * 1024;
    unsigned short* wob  = wvb + 1024 * 1024;
    unsigned short* relb = wob + 1024 * 1024;

    cvt_all<<<dim3(1024, 5), 256, 0, stream>>>(wq, wk, wv, wo, rel,
                                               wqb, wkb, wvb, wob, relb);

    ln_all<<<dim3(M_PAD, 3), 256, 0, stream>>>(q, k, v, ln_g, ln_b, qn, kn, vn);

    gemm_qkv<<<dim3(8, 32, 3), 256, 0, stream>>>(qn, kn, vn, wqb, wkb, wvb,
                                                 bq, bk, bv, qh, kh, vt);

    attn_mfma<<<512, 512, 0, stream>>>(qh, kh, vt, relb, aout);

    gemm_out<<<dim3(8, 32), 256, 0, stream>>>(aout, wob, bo, q, out);
}

// Round 11
// 202.073 us; speedup vs baseline: 1.2299x; 1.2299x over previous
//
#include <hip/hip_runtime.h>
#include <hip/hip_bf16.h>

#define D_MODEL 1024
#define N_HEAD  16
#define D_K     64
#define MAX_LEN 1000
#define B_      4
#define S_      1000
#define S_PAD   1024
#define M_PAD   (B_ * S_PAD)       // 4096
#define M_REAL  (B_ * S_)          // 4000
#define LN_EPS  1e-5f
#define SCALE_L2E 0.1803368801111204f   // 0.125 * log2(e)
#define REL_ROWS (2*MAX_LEN-1)     // 1999

typedef __attribute__((ext_vector_type(8))) short short8;
typedef __attribute__((ext_vector_type(4))) float f32x4;

__device__ __forceinline__ unsigned short f2b(float f) {
    unsigned u = __builtin_bit_cast(unsigned, f);
    u = (u + 0x7FFFu + ((u >> 16) & 1u)) >> 16;
    return (unsigned short)u;
}

__device__ __forceinline__ unsigned short f2b_trunc(float f) {
    return (unsigned short)(__builtin_bit_cast(unsigned, f) >> 16);
}

__device__ __forceinline__ float b2f(unsigned short u) {
    return __builtin_bit_cast(float, (unsigned)u << 16);
}

__device__ __forceinline__ f32x4 mfma16(short8 a, short8 b, f32x4 c) {
    return __builtin_amdgcn_mfma_f32_16x16x32_bf16(a, b, c, 0, 0, 0);
}

__device__ __forceinline__ void gload_lds16(const void* g, void* l) {
    __builtin_amdgcn_global_load_lds(
        (const __attribute__((address_space(1))) unsigned int*)g,
        (__attribute__((address_space(3))) unsigned int*)l, 16, 0, 0);
}

// ---------------- merged fp32 -> bf16 convert (5 tensors) ----------------
__global__ void cvt_all(const float* __restrict__ s0, const float* __restrict__ s1,
                        const float* __restrict__ s2, const float* __restrict__ s3,
                        const float* __restrict__ s4,
                        unsigned short* __restrict__ d0, unsigned short* __restrict__ d1,
                        unsigned short* __restrict__ d2, unsigned short* __restrict__ d3,
                        unsigned short* __restrict__ d4) {
    int y = blockIdx.y;
    const float* in; unsigned short* out; int n4;
    switch (y) {
        case 0: in = s0; out = d0; n4 = 262144; break;
        case 1: in = s1; out = d1; n4 = 262144; break;
        case 2: in = s2; out = d2; n4 = 262144; break;
        case 3: in = s3; out = d3; n4 = 262144; break;
        default: in = s4; out = d4; n4 = REL_ROWS * D_K / 4; break;
    }
    int i = blockIdx.x * blockDim.x + threadIdx.x;
    if (i >= n4) return;
    float4 v = ((const float4*)in)[i];
    ushort4 o;
    o.x = f2b(v.x); o.y = f2b(v.y); o.z = f2b(v.z); o.w = f2b(v.w);
    ((ushort4*)out)[i] = o;
}

// ---------------- merged LayerNorm x3 -> bf16, padded rows zeroed ----------------
__global__ void ln_all(const float* __restrict__ xq, const float* __restrict__ xk,
                       const float* __restrict__ xv, const float* __restrict__ g,
                       const float* __restrict__ beta,
                       unsigned short* __restrict__ yq, unsigned short* __restrict__ yk,
                       unsigned short* __restrict__ yv) {
    int which = blockIdx.y;
    const float* x = which == 0 ? xq : which == 1 ? xk : xv;
    unsigned short* y = which == 0 ? yq : which == 1 ? yk : yv;

    int r = blockIdx.x;            // padded row index
    int b = r >> 10, i = r & 1023;
    unsigned short* yr = y + (size_t)r * D_MODEL;
    int tid = threadIdx.x;
    if (i >= S_) {
#pragma unroll
        for (int l = 0; l < 4; ++l) yr[tid + l * 256] = 0;
        return;
    }
    const float* xr = x + ((size_t)b * S_ + i) * D_MODEL;
    float v[4];
    float s = 0.f, sq = 0.f;
#pragma unroll
    for (int l = 0; l < 4; ++l) {
        v[l] = xr[tid + l * 256];
        s += v[l];
        sq += v[l] * v[l];
    }
#pragma unroll
    for (int o = 32; o > 0; o >>= 1) {
        s += __shfl_down(s, o, 64);
        sq += __shfl_down(sq, o, 64);
    }
    __shared__ float rs[4], rq[4];
    if ((tid & 63) == 0) { rs[tid >> 6] = s; rq[tid >> 6] = sq; }
    __syncthreads();
    if (tid == 0) {
        rs[0] = rs[0] + rs[1] + rs[2] + rs[3];
        rq[0] = rq[0] + rq[1] + rq[2] + rq[3];
    }
    __syncthreads();
    float mu = rs[0] * (1.0f / D_MODEL);
    float var = rq[0] * (1.0f / D_MODEL) - mu * mu;
    float rstd = rsqrtf(var + LN_EPS);
#pragma unroll
    for (int l = 0; l < 4; ++l) {
        int c = tid + l * 256;
        yr[c] = f2b((v[l] - mu) * rstd * g[c] + beta[c]);
    }
}

// ---------------- GEMM core ----------------
// MODE 0: head layout [b,h,i,d]; MODE 1: transposed head [b,h,d,i]; MODE 2: fp32 +resid
template<int MODE>
__device__ __forceinline__ void gemm_body(
        const unsigned short* __restrict__ X, const unsigned short* __restrict__ W,
        const float* __restrict__ bias, const float* __restrict__ resid,
        unsigned short* __restrict__ Yb, float* __restrict__ Yf,
        unsigned short* As, unsigned short* Bs, int row0, int col0) {
    int tid = threadIdx.x;
    int lane = tid & 63, w = tid >> 6;
    int wr = w >> 1, wc = w & 1;
    int fr = lane & 15, fk = (lane >> 4) * 8;

    f32x4 acc[4][4];
#pragma unroll
    for (int fm = 0; fm < 4; ++fm)
#pragma unroll
        for (int fn = 0; fn < 4; ++fn) acc[fm][fn] = (f32x4)0.f;

    int c0 = (w * 2 + 0) * 64 + lane;
    int c1 = (w * 2 + 1) * 64 + lane;
    const unsigned short* xs0 = X + (size_t)(row0 + (c0 >> 2)) * 1024 + (c0 & 3) * 8;
    const unsigned short* xs1 = X + (size_t)(row0 + (c1 >> 2)) * 1024 + (c1 & 3) * 8;
    const unsigned short* ws0 = W + (size_t)(col0 + (c0 >> 2)) * 1024 + (c0 & 3) * 8;
    const unsigned short* ws1 = W + (size_t)(col0 + (c1 >> 2)) * 1024 + (c1 & 3) * 8;
    unsigned short* ad0 = As + (w * 2 + 0) * 512;
    unsigned short* ad1 = As + (w * 2 + 1) * 512;
    unsigned short* bd0 = Bs + (w * 2 + 0) * 512;
    unsigned short* bd1 = Bs + (w * 2 + 1) * 512;

    for (int k0 = 0; k0 < 1024; k0 += 32) {
        gload_lds16(xs0 + k0, ad0);
        gload_lds16(xs1 + k0, ad1);
        gload_lds16(ws0 + k0, bd0);
        gload_lds16(ws1 + k0, bd1);
        __syncthreads();
        short8 a[4], b[4];
#pragma unroll
        for (int fm = 0; fm < 4; ++fm)
            a[fm] = *(const short8*)(As + (wr * 64 + fm * 16 + fr) * 32 + fk);
#pragma unroll
        for (int fn = 0; fn < 4; ++fn)
            b[fn] = *(const short8*)(Bs + (wc * 64 + fn * 16 + fr) * 32 + fk);
#pragma unroll
        for (int fm = 0; fm < 4; ++fm)
#pragma unroll
            for (int fn = 0; fn < 4; ++fn)
                acc[fm][fn] = mfma16(a[fm], b[fn], acc[fm][fn]);
        __syncthreads();
    }

#pragma unroll
    for (int fm = 0; fm < 4; ++fm) {
#pragma unroll
        for (int fn = 0; fn < 4; ++fn) {
            int cg = col0 + wc * 64 + fn * 16 + fr;
            float bv = bias[cg];
#pragma unroll
            for (int r = 0; r < 4; ++r) {
                int rg = row0 + wr * 64 + fm * 16 + (lane >> 4) * 4 + r;
                float val = acc[fm][fn][r] + bv;
                int b_ = rg >> 10, i = rg & 1023;
                if (MODE == 0) {
                    int h = cg >> 6, d = cg & 63;
                    Yb[(((size_t)(b_ * N_HEAD + h)) * S_PAD + i) * D_K + d] = f2b(val);
                } else if (MODE == 1) {
                    int h = cg >> 6, d = cg & 63;
                    Yb[(((size_t)(b_ * N_HEAD + h)) * D_K + d) * S_PAD + i] = f2b(val);
                } else {
                    if (i < S_) {
                        size_t orow = (size_t)b_ * S_ + i;
                        Yf[orow * 1024 + cg] = val + resid[orow * 1024 + cg];
                    }
                }
            }
        }
    }
}

// merged Q/K/V projections: grid (8, 32, 3)
__global__ __launch_bounds__(256) void gemm_qkv(
        const unsigned short* __restrict__ qn, const unsigned short* __restrict__ kn,
        const unsigned short* __restrict__ vn,
        const unsigned short* __restrict__ wqb, const unsigned short* __restrict__ wkb,
        const unsigned short* __restrict__ wvb,
        const float* __restrict__ bq, const float* __restrict__ bk,
        const float* __restrict__ bv,
        unsigned short* __restrict__ qh, unsigned short* __restrict__ kh,
        unsigned short* __restrict__ vt) {
    __shared__ __align__(16) unsigned short As[128 * 32];
    __shared__ __align__(16) unsigned short Bs[128 * 32];
    int z = blockIdx.z;
    int row0 = blockIdx.y * 128, col0 = blockIdx.x * 128;
    if (z == 0)
        gemm_body<0>(qn, wqb, bq, nullptr, qh, nullptr, As, Bs, row0, col0);
    else if (z == 1)
        gemm_body<0>(kn, wkb, bk, nullptr, kh, nullptr, As, Bs, row0, col0);
    else
        gemm_body<1>(vn, wvb, bv, nullptr, vt, nullptr, As, Bs, row0, col0);
}

// final output projection + residual
__global__ __launch_bounds__(256) void gemm_out(
        const unsigned short* __restrict__ X, const unsigned short* __restrict__ W,
        const float* __restrict__ bias, const float* __restrict__ resid,
        float* __restrict__ Yf) {
    __shared__ __align__(16) unsigned short As[128 * 32];
    __shared__ __align__(16) unsigned short Bs[128 * 32];
    gemm_body<2>(X, W, bias, resid, nullptr, Yf, As, Bs, blockIdx.y * 128, blockIdx.x * 128);
}

// ---------------- Flash attention: dbuf K/V pipeline, 2 Q-slabs/wave (r9 base) ----------------
// + r10-proven VALU trims: defer-max, truncating bf16 converts, mask hoist; + setprio.
#define QRW 84    // QR scratch stride (79 used); 84 => 4-row bank shift of 8 (conflict-free-ish)
#define PW  72    // P scratch stride (64 used), same buffer as QR
__device__ __forceinline__ void attn_slab(
        const unsigned short* __restrict__ Kc, const unsigned short* __restrict__ Vc,
        unsigned short* __restrict__ qp, const short8 rl[5][2],
        short8 aq0, short8 aq1, f32x4* accO, float* mrun, float* lrun,
        bool mask_needed, int j0, int fr, int fk8, int rgrp, int rsw) {
    // ---- QK^T from LDS ----
    f32x4 accS[4];
#pragma unroll
    for (int fj = 0; fj < 4; ++fj) accS[fj] = (f32x4)0.f;
    __builtin_amdgcn_s_setprio(1);
#pragma unroll
    for (int fj = 0; fj < 4; ++fj) {
        int kb = (fj * 16 + fr) * 64 + fk8;
        accS[fj] = mfma16(aq0, *(const short8*)(Kc + (kb ^ rsw)), accS[fj]);
        accS[fj] = mfma16(aq1, *(const short8*)(Kc + ((kb + 32) ^ rsw)), accS[fj]);
    }
    // ---- Q @ relband^T; spill (truncated bf16) for diagonal gather ----
#pragma unroll
    for (int fu = 0; fu < 5; ++fu) {
        f32x4 qr = (f32x4)0.f;
        qr = mfma16(aq0, rl[fu][0], qr);
        qr = mfma16(aq1, rl[fu][1], qr);
#pragma unroll
        for (int r = 0; r < 4; ++r)
            qp[(rgrp + r) * QRW + fu * 16 + fr] = f2b_trunc(qr[r]);
    }
    __builtin_amdgcn_s_setprio(0);

    // ---- assemble scores (mask hoisted out of hot path) ----
    float sc[4][4];
#pragma unroll
    for (int fj = 0; fj < 4; ++fj) {
        int j_loc = fj * 16 + fr;
#pragma unroll
        for (int r = 0; r < 4; ++r) {
            int col = rgrp + r - j_loc + 63;   // in [0,78]
            sc[fj][r] = (accS[fj][r] + b2f(qp[(rgrp + r) * QRW + col])) * SCALE_L2E;
        }
    }
    if (mask_needed) {
#pragma unroll
        for (int fj = 0; fj < 4; ++fj) {
            int j_loc = fj * 16 + fr;
            if (j0 + j_loc >= S_) {
#pragma unroll
                for (int r = 0; r < 4; ++r) sc[fj][r] = -3e38f;
            }
        }
    }

    // ---- row max ----
    float pm[4];
#pragma unroll
    for (int r = 0; r < 4; ++r)
        pm[r] = fmaxf(fmaxf(sc[0][r], sc[1][r]), fmaxf(sc[2][r], sc[3][r]));
#pragma unroll
    for (int mask = 1; mask <= 8; mask <<= 1)
#pragma unroll
        for (int r = 0; r < 4; ++r)
            pm[r] = fmaxf(pm[r], __shfl_xor(pm[r], mask, 64));

    // ---- defer-max: rescale only when max grew by > 8 (log2 units) ----
    float dmax = fmaxf(fmaxf(pm[0] - mrun[0], pm[1] - mrun[1]),
                       fmaxf(pm[2] - mrun[2], pm[3] - mrun[3]));
    if (!__all(dmax <= 8.0f)) {
#pragma unroll
        for (int r = 0; r < 4; ++r) {
            float mn = fmaxf(mrun[r], pm[r]);
            float scl = __builtin_amdgcn_exp2f(mrun[r] - mn);
            mrun[r] = mn;
            lrun[r] *= scl;
#pragma unroll
            for (int fd = 0; fd < 4; ++fd) accO[fd][r] *= scl;
        }
    }

    // ---- exp (base-2) + truncated bf16 P store ----
    float rsum[4];
#pragma unroll
    for (int r = 0; r < 4; ++r) rsum[r] = 0.f;
#pragma unroll
    for (int fj = 0; fj < 4; ++fj) {
#pragma unroll
        for (int r = 0; r < 4; ++r) {
            float p = __builtin_amdgcn_exp2f(sc[fj][r] - mrun[r]);
            rsum[r] += p;
            qp[(rgrp + r) * PW + fj * 16 + fr] = f2b_trunc(p);
        }
    }
#pragma unroll
    for (int mask = 1; mask <= 8; mask <<= 1)
#pragma unroll
        for (int r = 0; r < 4; ++r)
            rsum[r] += __shfl_xor(rsum[r], mask, 64);
#pragma unroll
    for (int r = 0; r < 4; ++r) lrun[r] += rsum[r];

    // ---- PV from LDS ----
    short8 ap0 = *(const short8*)(qp + fr * PW + fk8);
    short8 ap1 = *(const short8*)(qp + fr * PW + 32 + fk8);
    __builtin_amdgcn_s_setprio(1);
#pragma unroll
    for (int fd = 0; fd < 4; ++fd) {
        int vb = (fd * 16 + fr) * 64 + fk8;
        accO[fd] = mfma16(ap0, *(const short8*)(Vc + (vb ^ rsw)), accO[fd]);
        accO[fd] = mfma16(ap1, *(const short8*)(Vc + ((vb + 32) ^ rsw)), accO[fd]);
    }
    __builtin_amdgcn_s_setprio(0);
}

__global__ __launch_bounds__(256, 4) void attn_mfma(
        const unsigned short* __restrict__ qh, const unsigned short* __restrict__ kh,
        const unsigned short* __restrict__ vt, const unsigned short* __restrict__ relb,
        unsigned short* __restrict__ aout) {
    __shared__ __align__(16) unsigned short Ks[2][64 * 64];   // 16 KB
    __shared__ __align__(16) unsigned short Vs[2][64 * 64];   // 16 KB
    __shared__ __align__(16) unsigned short QP[4][16 * QRW];  // 10.5 KB

    int tid = threadIdx.x, lane = tid & 63, w = tid >> 6;
    int bid = blockIdx.x;                      // 512 blocks
    int swz = (bid & 7) * 64 + (bid >> 3);     // XCD-chunked, bijective (512 = 8*64)
    int bh = swz >> 3;                         // uniform across block
    int i0a = (((swz & 7) * 8) + 2 * w) * 16;  // slab a; slab b = i0a + 16
    int fr = lane & 15, fk8 = (lane >> 4) * 8, rgrp = (lane >> 4) * 4;
    int rsw = (fr & 7) << 3;                   // read-side XOR (ushort units)

    const unsigned short* kbase = kh + (size_t)bh * S_PAD * D_K;   // [i][d]
    const unsigned short* vtbase = vt + (size_t)bh * D_K * S_PAD;  // [d][i]

    const unsigned short* qpa = qh + ((size_t)bh * S_PAD + i0a + fr) * D_K + fk8;
    short8 aqa0 = *(const short8*)(qpa);
    short8 aqa1 = *(const short8*)(qpa + 32);
    const unsigned short* qpb = qpa + 16 * D_K;
    short8 aqb0 = *(const short8*)(qpb);
    short8 aqb1 = *(const short8*)(qpb + 32);

    f32x4 accOa[4], accOb[4];
    float mruna[4], lruna[4], mrunb[4], lrunb[4];
#pragma unroll
    for (int fd = 0; fd < 4; ++fd) { accOa[fd] = (f32x4)0.f; accOb[fd] = (f32x4)0.f; }
#pragma unroll
    for (int r = 0; r < 4; ++r) {
        mruna[r] = -3e38f; lruna[r] = 0.f;
        mrunb[r] = -3e38f; lrunb[r] = 0.f;
    }

    unsigned short* qp = QP[w];
    int row_in = lane >> 3, slot = lane & 7;

    auto stage = [&](int buf, int it2) {
        int j0s = it2 * 64;
#pragma unroll
        for (int cc = 0; cc < 2; ++cc) {
            int c = w * 2 + cc;
            int r = c * 8 + row_in;
            gload_lds16(kbase + (size_t)(j0s + r) * 64 + (slot ^ row_in) * 8,
                        &Ks[buf][c * 512]);
        }
#pragma unroll
        for (int cc = 0; cc < 2; ++cc) {
            int c = w * 2 + cc;
            int d = c * 8 + row_in;
            gload_lds16(vtbase + (size_t)d * S_PAD + j0s + (slot ^ row_in) * 8,
                        &Vs[buf][c * 512]);
        }
    };

    stage(0, 0);
    __syncthreads();   // tile 0 landed (compiler drains vmcnt at barrier)

    for (int it = 0; it < 16; ++it) {
        int cur = it & 1, j0 = it * 64;
        bool mask_needed = (j0 + 63 >= S_);

        // slab-a rel fragments issued BEFORE stage (counted vmcnt, not drain)
        short8 rla[5][2];
        int ub = i0a - j0 + (S_ - D_K);
#pragma unroll
        for (int fu = 0; fu < 5; ++fu) {
            int u = ub + fu * 16 + fr;
            u = u < 0 ? 0 : (u > REL_ROWS - 1 ? REL_ROWS - 1 : u);
            const unsigned short* rp = relb + (size_t)u * D_K + fk8;
            rla[fu][0] = *(const short8*)(rp);
            rla[fu][1] = *(const short8*)(rp + 32);
        }
        __builtin_amdgcn_sched_barrier(0);   // keep rel loads ahead of stage issue

        if (it < 15) stage(cur ^ 1, it + 1);  // prefetch next tile (other buffer)

        attn_slab(Ks[cur], Vs[cur], qp, rla, aqa0, aqa1, accOa, mruna, lruna,
                  mask_needed, j0, fr, fk8, rgrp, rsw);

        // slab b: rel loads issued after stage; use point is far past stage latency
        short8 rlb[5][2];
        int ub2 = ub + 16;
#pragma unroll
        for (int fu = 0; fu < 5; ++fu) {
            int u = ub2 + fu * 16 + fr;
            u = u < 0 ? 0 : (u > REL_ROWS - 1 ? REL_ROWS - 1 : u);
            const unsigned short* rp = relb + (size_t)u * D_K + fk8;
            rlb[fu][0] = *(const short8*)(rp);
            rlb[fu][1] = *(const short8*)(rp + 32);
        }
        attn_slab(Ks[cur], Vs[cur], qp, rlb, aqb0, aqb1, accOb, mrunb, lrunb,
                  mask_needed, j0, fr, fk8, rgrp, rsw);

        __syncthreads();   // next tile landed; all waves done with Ks/Vs[cur]
    }

    // ---- normalize + store both slabs ----
    int b_ = bh >> 4, h = bh & 15;
#pragma unroll
    for (int r = 0; r < 4; ++r) {
        float inva = 1.0f / lruna[r];
        float invb = 1.0f / lrunb[r];
        int ma = b_ * S_PAD + i0a + rgrp + r;
        int mb = ma + 16;
#pragma unroll
        for (int fd = 0; fd < 4; ++fd) {
            int c = h * D_K + fd * 16 + fr;
            aout[(size_t)ma * D_MODEL + c] = f2b(accOa[fd][r] * inva);
            aout[(size_t)mb * D_MODEL + c] = f2b(accOb[fd][r] * invb);
        }
    }
}

extern "C" void kernel_launch(void* const* d_in, const int* in_sizes, int n_in,
                              void* d_out, int out_size, void* d_ws, size_t ws_size,
                              hipStream_t stream) {
    const float* q    = (const float*)d_in[0];
    const float* k    = (const float*)d_in[1];
    const float* v    = (const float*)d_in[2];
    const float* ln_g = (const float*)d_in[3];
    const float* ln_b = (const float*)d_in[4];
    const float* wq   = (const float*)d_in[5];
    const float* bq   = (const float*)d_in[6];
    const float* wk   = (const float*)d_in[7];
    const float* bk   = (const float*)d_in[8];
    const float* wv   = (const float*)d_in[9];
    const float* bv   = (const float*)d_in[10];
    const float* wo   = (const float*)d_in[11];
    const float* bo   = (const float*)d_in[12];
    const float* rel  = (const float*)d_in[13];
    float* out = (float*)d_out;

    const size_t TSZ = (size_t)M_PAD * D_MODEL;     // 4,194,304 ushorts
    unsigned short* ws   = (unsigned short*)d_ws;
    unsigned short* qn   = ws;
    unsigned short* kn   = qn + TSZ;
    unsigned short* vn   = kn + TSZ;
    unsigned short* qh   = vn + TSZ;
    unsigned short* kh   = qh + TSZ;
    unsigned short* vt   = kh + TSZ;
    unsigned short* aout = vt + TSZ;
    unsigned short* wqb  = aout + TSZ;
    unsigned short* wkb  = wqb + 1024 * 1024;
    unsigned short* wvb  = wkb + 1024 * 1024;
    unsigned short* wob  = wvb + 1024 * 1024;
    unsigned short* relb = wob + 1024 * 1024;

    cvt_all<<<dim3(1024, 5), 256, 0, stream>>>(wq, wk, wv, wo, rel,
                                               wqb, wkb, wvb, wob, relb);

    ln_all<<<dim3(M_PAD, 3), 256, 0, stream>>>(q, k, v, ln_g, ln_b, qn, kn, vn);

    gemm_qkv<<<dim3(8, 32, 3), 256, 0, stream>>>(qn, kn, vn, wqb, wkb, wvb,
                                                 bq, bk, bv, qh, kh, vt);

    attn_mfma<<<512, 256, 0, stream>>>(qh, kh, vt, relb, aout);

    gemm_out<<<dim3(8, 32), 256, 0, stream>>>(aout, wob, bo, q, out);
}

// Round 12
// 197.040 us; speedup vs baseline: 1.2613x; 1.0255x over previous
//
#include <hip/hip_runtime.h>
#include <hip/hip_bf16.h>

#define D_MODEL 1024
#define N_HEAD  16
#define D_K     64
#define MAX_LEN 1000
#define B_      4
#define S_      1000
#define S_PAD   1024
#define M_PAD   (B_ * S_PAD)       // 4096
#define M_REAL  (B_ * S_)          // 4000
#define LN_EPS  1e-5f
#define SCALE_L2E 0.1803368801111204f   // 0.125 * log2(e)
#define REL_ROWS (2*MAX_LEN-1)     // 1999

typedef __attribute__((ext_vector_type(8))) short short8;
typedef __attribute__((ext_vector_type(4))) float f32x4;

__device__ __forceinline__ unsigned short f2b(float f) {
    unsigned u = __builtin_bit_cast(unsigned, f);
    u = (u + 0x7FFFu + ((u >> 16) & 1u)) >> 16;
    return (unsigned short)u;
}

__device__ __forceinline__ unsigned short f2b_trunc(float f) {
    return (unsigned short)(__builtin_bit_cast(unsigned, f) >> 16);
}

__device__ __forceinline__ float b2f(unsigned short u) {
    return __builtin_bit_cast(float, (unsigned)u << 16);
}

__device__ __forceinline__ f32x4 mfma16(short8 a, short8 b, f32x4 c) {
    return __builtin_amdgcn_mfma_f32_16x16x32_bf16(a, b, c, 0, 0, 0);
}

__device__ __forceinline__ void gload_lds16(const void* g, void* l) {
    __builtin_amdgcn_global_load_lds(
        (const __attribute__((address_space(1))) unsigned int*)g,
        (__attribute__((address_space(3))) unsigned int*)l, 16, 0, 0);
}

// ---------------- merged fp32 -> bf16 convert (5 tensors) ----------------
__global__ void cvt_all(const float* __restrict__ s0, const float* __restrict__ s1,
                        const float* __restrict__ s2, const float* __restrict__ s3,
                        const float* __restrict__ s4,
                        unsigned short* __restrict__ d0, unsigned short* __restrict__ d1,
                        unsigned short* __restrict__ d2, unsigned short* __restrict__ d3,
                        unsigned short* __restrict__ d4) {
    int y = blockIdx.y;
    const float* in; unsigned short* out; int n4;
    switch (y) {
        case 0: in = s0; out = d0; n4 = 262144; break;
        case 1: in = s1; out = d1; n4 = 262144; break;
        case 2: in = s2; out = d2; n4 = 262144; break;
        case 3: in = s3; out = d3; n4 = 262144; break;
        default: in = s4; out = d4; n4 = REL_ROWS * D_K / 4; break;
    }
    int i = blockIdx.x * blockDim.x + threadIdx.x;
    if (i >= n4) return;
    float4 v = ((const float4*)in)[i];
    ushort4 o;
    o.x = f2b(v.x); o.y = f2b(v.y); o.z = f2b(v.z); o.w = f2b(v.w);
    ((ushort4*)out)[i] = o;
}

// ---------------- merged LayerNorm x3 -> bf16, padded rows zeroed ----------------
__global__ void ln_all(const float* __restrict__ xq, const float* __restrict__ xk,
                       const float* __restrict__ xv, const float* __restrict__ g,
                       const float* __restrict__ beta,
                       unsigned short* __restrict__ yq, unsigned short* __restrict__ yk,
                       unsigned short* __restrict__ yv) {
    int which = blockIdx.y;
    const float* x = which == 0 ? xq : which == 1 ? xk : xv;
    unsigned short* y = which == 0 ? yq : which == 1 ? yk : yv;

    int r = blockIdx.x;            // padded row index
    int b = r >> 10, i = r & 1023;
    unsigned short* yr = y + (size_t)r * D_MODEL;
    int tid = threadIdx.x;
    if (i >= S_) {
#pragma unroll
        for (int l = 0; l < 4; ++l) yr[tid + l * 256] = 0;
        return;
    }
    const float* xr = x + ((size_t)b * S_ + i) * D_MODEL;
    float v[4];
    float s = 0.f, sq = 0.f;
#pragma unroll
    for (int l = 0; l < 4; ++l) {
        v[l] = xr[tid + l * 256];
        s += v[l];
        sq += v[l] * v[l];
    }
#pragma unroll
    for (int o = 32; o > 0; o >>= 1) {
        s += __shfl_down(s, o, 64);
        sq += __shfl_down(sq, o, 64);
    }
    __shared__ float rs[4], rq[4];
    if ((tid & 63) == 0) { rs[tid >> 6] = s; rq[tid >> 6] = sq; }
    __syncthreads();
    if (tid == 0) {
        rs[0] = rs[0] + rs[1] + rs[2] + rs[3];
        rq[0] = rq[0] + rq[1] + rq[2] + rq[3];
    }
    __syncthreads();
    float mu = rs[0] * (1.0f / D_MODEL);
    float var = rq[0] * (1.0f / D_MODEL) - mu * mu;
    float rstd = rsqrtf(var + LN_EPS);
#pragma unroll
    for (int l = 0; l < 4; ++l) {
        int c = tid + l * 256;
        yr[c] = f2b((v[l] - mu) * rstd * g[c] + beta[c]);
    }
}

// ---------------- GEMM core ----------------
// MODE 0: head layout [b,h,i,d]; MODE 1: transposed head [b,h,d,i]; MODE 2: fp32 +resid
template<int MODE>
__device__ __forceinline__ void gemm_body(
        const unsigned short* __restrict__ X, const unsigned short* __restrict__ W,
        const float* __restrict__ bias, const float* __restrict__ resid,
        unsigned short* __restrict__ Yb, float* __restrict__ Yf,
        unsigned short* As, unsigned short* Bs, int row0, int col0) {
    int tid = threadIdx.x;
    int lane = tid & 63, w = tid >> 6;
    int wr = w >> 1, wc = w & 1;
    int fr = lane & 15, fk = (lane >> 4) * 8;

    f32x4 acc[4][4];
#pragma unroll
    for (int fm = 0; fm < 4; ++fm)
#pragma unroll
        for (int fn = 0; fn < 4; ++fn) acc[fm][fn] = (f32x4)0.f;

    int c0 = (w * 2 + 0) * 64 + lane;
    int c1 = (w * 2 + 1) * 64 + lane;
    const unsigned short* xs0 = X + (size_t)(row0 + (c0 >> 2)) * 1024 + (c0 & 3) * 8;
    const unsigned short* xs1 = X + (size_t)(row0 + (c1 >> 2)) * 1024 + (c1 & 3) * 8;
    const unsigned short* ws0 = W + (size_t)(col0 + (c0 >> 2)) * 1024 + (c0 & 3) * 8;
    const unsigned short* ws1 = W + (size_t)(col0 + (c1 >> 2)) * 1024 + (c1 & 3) * 8;
    unsigned short* ad0 = As + (w * 2 + 0) * 512;
    unsigned short* ad1 = As + (w * 2 + 1) * 512;
    unsigned short* bd0 = Bs + (w * 2 + 0) * 512;
    unsigned short* bd1 = Bs + (w * 2 + 1) * 512;

    for (int k0 = 0; k0 < 1024; k0 += 32) {
        gload_lds16(xs0 + k0, ad0);
        gload_lds16(xs1 + k0, ad1);
        gload_lds16(ws0 + k0, bd0);
        gload_lds16(ws1 + k0, bd1);
        __syncthreads();
        short8 a[4], b[4];
#pragma unroll
        for (int fm = 0; fm < 4; ++fm)
            a[fm] = *(const short8*)(As + (wr * 64 + fm * 16 + fr) * 32 + fk);
#pragma unroll
        for (int fn = 0; fn < 4; ++fn)
            b[fn] = *(const short8*)(Bs + (wc * 64 + fn * 16 + fr) * 32 + fk);
#pragma unroll
        for (int fm = 0; fm < 4; ++fm)
#pragma unroll
            for (int fn = 0; fn < 4; ++fn)
                acc[fm][fn] = mfma16(a[fm], b[fn], acc[fm][fn]);
        __syncthreads();
    }

#pragma unroll
    for (int fm = 0; fm < 4; ++fm) {
#pragma unroll
        for (int fn = 0; fn < 4; ++fn) {
            int cg = col0 + wc * 64 + fn * 16 + fr;
            float bv = bias[cg];
#pragma unroll
            for (int r = 0; r < 4; ++r) {
                int rg = row0 + wr * 64 + fm * 16 + (lane >> 4) * 4 + r;
                float val = acc[fm][fn][r] + bv;
                int b_ = rg >> 10, i = rg & 1023;
                if (MODE == 0) {
                    int h = cg >> 6, d = cg & 63;
                    Yb[(((size_t)(b_ * N_HEAD + h)) * S_PAD + i) * D_K + d] = f2b(val);
                } else if (MODE == 1) {
                    int h = cg >> 6, d = cg & 63;
                    Yb[(((size_t)(b_ * N_HEAD + h)) * D_K + d) * S_PAD + i] = f2b(val);
                } else {
                    if (i < S_) {
                        size_t orow = (size_t)b_ * S_ + i;
                        Yf[orow * 1024 + cg] = val + resid[orow * 1024 + cg];
                    }
                }
            }
        }
    }
}

// merged Q/K/V projections: grid (8, 32, 3)
__global__ __launch_bounds__(256) void gemm_qkv(
        const unsigned short* __restrict__ qn, const unsigned short* __restrict__ kn,
        const unsigned short* __restrict__ vn,
        const unsigned short* __restrict__ wqb, const unsigned short* __restrict__ wkb,
        const unsigned short* __restrict__ wvb,
        const float* __restrict__ bq, const float* __restrict__ bk,
        const float* __restrict__ bv,
        unsigned short* __restrict__ qh, unsigned short* __restrict__ kh,
        unsigned short* __restrict__ vt) {
    __shared__ __align__(16) unsigned short As[128 * 32];
    __shared__ __align__(16) unsigned short Bs[128 * 32];
    int z = blockIdx.z;
    int row0 = blockIdx.y * 128, col0 = blockIdx.x * 128;
    if (z == 0)
        gemm_body<0>(qn, wqb, bq, nullptr, qh, nullptr, As, Bs, row0, col0);
    else if (z == 1)
        gemm_body<0>(kn, wkb, bk, nullptr, kh, nullptr, As, Bs, row0, col0);
    else
        gemm_body<1>(vn, wvb, bv, nullptr, vt, nullptr, As, Bs, row0, col0);
}

// final output projection + residual
__global__ __launch_bounds__(256) void gemm_out(
        const unsigned short* __restrict__ X, const unsigned short* __restrict__ W,
        const float* __restrict__ bias, const float* __restrict__ resid,
        float* __restrict__ Yf) {
    __shared__ __align__(16) unsigned short As[128 * 32];
    __shared__ __align__(16) unsigned short Bs[128 * 32];
    gemm_body<2>(X, W, bias, resid, nullptr, Yf, As, Bs, blockIdx.y * 128, blockIdx.x * 128);
}

// ---------------- Flash attention: dbuf K/V, 2 slabs/wave, counted-vmcnt rel ----------------
#define QRW 84    // QR scratch stride (79 used)
#define PW  72    // P scratch stride (64 used), same buffer as QR
__device__ __forceinline__ void attn_slab(
        const unsigned short* __restrict__ Kc, const unsigned short* __restrict__ Vc,
        unsigned short* __restrict__ qp, const short8 (*rl)[2],
        short8 aq0, short8 aq1, f32x4* accO, float* mrun, float* lrun,
        bool mask_needed, int j0, int fr, int fk8, int rgrp, int rsw) {
    // ---- QK^T from LDS ----
    f32x4 accS[4];
#pragma unroll
    for (int fj = 0; fj < 4; ++fj) accS[fj] = (f32x4)0.f;
    __builtin_amdgcn_s_setprio(1);
#pragma unroll
    for (int fj = 0; fj < 4; ++fj) {
        int kb = (fj * 16 + fr) * 64 + fk8;
        accS[fj] = mfma16(aq0, *(const short8*)(Kc + (kb ^ rsw)), accS[fj]);
        accS[fj] = mfma16(aq1, *(const short8*)(Kc + ((kb + 32) ^ rsw)), accS[fj]);
    }
    // ---- Q @ relband^T; spill (truncated bf16) for diagonal gather ----
#pragma unroll
    for (int fu = 0; fu < 5; ++fu) {
        f32x4 qr = (f32x4)0.f;
        qr = mfma16(aq0, rl[fu][0], qr);
        qr = mfma16(aq1, rl[fu][1], qr);
#pragma unroll
        for (int r = 0; r < 4; ++r)
            qp[(rgrp + r) * QRW + fu * 16 + fr] = f2b_trunc(qr[r]);
    }
    __builtin_amdgcn_s_setprio(0);

    // ---- assemble scores (mask hoisted out of hot path) ----
    float sc[4][4];
#pragma unroll
    for (int fj = 0; fj < 4; ++fj) {
        int j_loc = fj * 16 + fr;
#pragma unroll
        for (int r = 0; r < 4; ++r) {
            int col = rgrp + r - j_loc + 63;   // in [0,78]
            sc[fj][r] = (accS[fj][r] + b2f(qp[(rgrp + r) * QRW + col])) * SCALE_L2E;
        }
    }
    if (mask_needed) {
#pragma unroll
        for (int fj = 0; fj < 4; ++fj) {
            int j_loc = fj * 16 + fr;
            if (j0 + j_loc >= S_) {
#pragma unroll
                for (int r = 0; r < 4; ++r) sc[fj][r] = -3e38f;
            }
        }
    }

    // ---- row max ----
    float pm[4];
#pragma unroll
    for (int r = 0; r < 4; ++r)
        pm[r] = fmaxf(fmaxf(sc[0][r], sc[1][r]), fmaxf(sc[2][r], sc[3][r]));
#pragma unroll
    for (int mask = 1; mask <= 8; mask <<= 1)
#pragma unroll
        for (int r = 0; r < 4; ++r)
            pm[r] = fmaxf(pm[r], __shfl_xor(pm[r], mask, 64));

    // ---- defer-max: rescale only when max grew by > 8 (log2 units) ----
    float dmax = fmaxf(fmaxf(pm[0] - mrun[0], pm[1] - mrun[1]),
                       fmaxf(pm[2] - mrun[2], pm[3] - mrun[3]));
    if (!__all(dmax <= 8.0f)) {
#pragma unroll
        for (int r = 0; r < 4; ++r) {
            float mn = fmaxf(mrun[r], pm[r]);
            float scl = __builtin_amdgcn_exp2f(mrun[r] - mn);
            mrun[r] = mn;
            lrun[r] *= scl;
#pragma unroll
            for (int fd = 0; fd < 4; ++fd) accO[fd][r] *= scl;
        }
    }

    // ---- exp (base-2) + truncated bf16 P store ----
    float rsum[4];
#pragma unroll
    for (int r = 0; r < 4; ++r) rsum[r] = 0.f;
#pragma unroll
    for (int fj = 0; fj < 4; ++fj) {
#pragma unroll
        for (int r = 0; r < 4; ++r) {
            float p = __builtin_amdgcn_exp2f(sc[fj][r] - mrun[r]);
            rsum[r] += p;
            qp[(rgrp + r) * PW + fj * 16 + fr] = f2b_trunc(p);
        }
    }
#pragma unroll
    for (int mask = 1; mask <= 8; mask <<= 1)
#pragma unroll
        for (int r = 0; r < 4; ++r)
            rsum[r] += __shfl_xor(rsum[r], mask, 64);
#pragma unroll
    for (int r = 0; r < 4; ++r) lrun[r] += rsum[r];

    // ---- PV from LDS ----
    short8 ap0 = *(const short8*)(qp + fr * PW + fk8);
    short8 ap1 = *(const short8*)(qp + fr * PW + 32 + fk8);
    __builtin_amdgcn_s_setprio(1);
#pragma unroll
    for (int fd = 0; fd < 4; ++fd) {
        int vb = (fd * 16 + fr) * 64 + fk8;
        accO[fd] = mfma16(ap0, *(const short8*)(Vc + (vb ^ rsw)), accO[fd]);
        accO[fd] = mfma16(ap1, *(const short8*)(Vc + ((vb + 32) ^ rsw)), accO[fd]);
    }
    __builtin_amdgcn_s_setprio(0);
}

__global__ __launch_bounds__(256, 2) void attn_mfma(
        const unsigned short* __restrict__ qh, const unsigned short* __restrict__ kh,
        const unsigned short* __restrict__ vt, const unsigned short* __restrict__ relb,
        unsigned short* __restrict__ aout) {
    __shared__ __align__(16) unsigned short Ks[2][64 * 64];   // 16 KB
    __shared__ __align__(16) unsigned short Vs[2][64 * 64];   // 16 KB
    __shared__ __align__(16) unsigned short QP[4][16 * QRW];  // 10.5 KB

    int tid = threadIdx.x, lane = tid & 63, w = tid >> 6;
    int bid = blockIdx.x;                      // 512 blocks
    int swz = (bid & 7) * 64 + (bid >> 3);     // XCD-chunked, bijective (512 = 8*64)
    int bh = swz >> 3;                         // uniform across block
    int i0a = (((swz & 7) * 8) + 2 * w) * 16;  // slab a; slab b = i0a + 16
    int fr = lane & 15, fk8 = (lane >> 4) * 8, rgrp = (lane >> 4) * 4;
    int rsw = (fr & 7) << 3;                   // read-side XOR (ushort units)

    const unsigned short* kbase = kh + (size_t)bh * S_PAD * D_K;   // [i][d]
    const unsigned short* vtbase = vt + (size_t)bh * D_K * S_PAD;  // [d][i]

    const unsigned short* qpa = qh + ((size_t)bh * S_PAD + i0a + fr) * D_K + fk8;
    short8 aqa0 = *(const short8*)(qpa);
    short8 aqa1 = *(const short8*)(qpa + 32);
    const unsigned short* qpb = qpa + 16 * D_K;
    short8 aqb0 = *(const short8*)(qpb);
    short8 aqb1 = *(const short8*)(qpb + 32);

    f32x4 accOa[4], accOb[4];
    float mruna[4], lruna[4], mrunb[4], lrunb[4];
#pragma unroll
    for (int fd = 0; fd < 4; ++fd) { accOa[fd] = (f32x4)0.f; accOb[fd] = (f32x4)0.f; }
#pragma unroll
    for (int r = 0; r < 4; ++r) {
        mruna[r] = -3e38f; lruna[r] = 0.f;
        mrunb[r] = -3e38f; lrunb[r] = 0.f;
    }

    unsigned short* qp = QP[w];
    int row_in = lane >> 3, slot = lane & 7;

    auto stage = [&](int buf, int it2) {
        int j0s = it2 * 64;
#pragma unroll
        for (int cc = 0; cc < 2; ++cc) {
            int c = w * 2 + cc;
            int r = c * 8 + row_in;
            gload_lds16(kbase + (size_t)(j0s + r) * 64 + (slot ^ row_in) * 8,
                        &Ks[buf][c * 512]);
        }
#pragma unroll
        for (int cc = 0; cc < 2; ++cc) {
            int c = w * 2 + cc;
            int d = c * 8 + row_in;
            gload_lds16(vtbase + (size_t)d * S_PAD + j0s + (slot ^ row_in) * 8,
                        &Vs[buf][c * 512]);
        }
    };

    stage(0, 0);
    __syncthreads();   // tile 0 landed

    for (int it = 0; it < 16; ++it) {
        int cur = it & 1, j0 = it * 64;
        bool mask_needed = (j0 + 63 >= S_);

        // ---- ALL rel fragments for BOTH slabs issued BEFORE stage ----
        // slab b's band is slab a's shifted one fragment: rl[k] at u = ub + k*16;
        // a uses rl[0..4], b uses rl[1..5]. 12 loads total (was 20).
        // Issue order (rel first, then stage) => rel waits are counted vmcnt,
        // never draining the stage prefetch mid-iteration.
        short8 rl[6][2];
        int ub = i0a - j0 + (S_ - D_K);
#pragma unroll
        for (int fu = 0; fu < 6; ++fu) {
            int u = ub + fu * 16 + fr;
            u = u < 0 ? 0 : (u > REL_ROWS - 1 ? REL_ROWS - 1 : u);
            const unsigned short* rp = relb + (size_t)u * D_K + fk8;
            rl[fu][0] = *(const short8*)(rp);
            rl[fu][1] = *(const short8*)(rp + 32);
        }
        __builtin_amdgcn_sched_barrier(0);   // pin rel loads ahead of stage issue

        if (it < 15) stage(cur ^ 1, it + 1);  // prefetch next tile (other buffer)

        attn_slab(Ks[cur], Vs[cur], qp, rl, aqa0, aqa1, accOa, mruna, lruna,
                  mask_needed, j0, fr, fk8, rgrp, rsw);
        attn_slab(Ks[cur], Vs[cur], qp, rl + 1, aqb0, aqb1, accOb, mrunb, lrunb,
                  mask_needed, j0, fr, fk8, rgrp, rsw);

        __syncthreads();   // next tile landed; all waves done with Ks/Vs[cur]
    }

    // ---- normalize + store both slabs ----
    int b_ = bh >> 4, h = bh & 15;
#pragma unroll
    for (int r = 0; r < 4; ++r) {
        float inva = 1.0f / lruna[r];
        float invb = 1.0f / lrunb[r];
        int ma = b_ * S_PAD + i0a + rgrp + r;
        int mb = ma + 16;
#pragma unroll
        for (int fd = 0; fd < 4; ++fd) {
            int c = h * D_K + fd * 16 + fr;
            aout[(size_t)ma * D_MODEL + c] = f2b(accOa[fd][r] * inva);
            aout[(size_t)mb * D_MODEL + c] = f2b(accOb[fd][r] * invb);
        }
    }
}

extern "C" void kernel_launch(void* const* d_in, const int* in_sizes, int n_in,
                              void* d_out, int out_size, void* d_ws, size_t ws_size,
                              hipStream_t stream) {
    const float* q    = (const float*)d_in[0];
    const float* k    = (const float*)d_in[1];
    const float* v    = (const float*)d_in[2];
    const float* ln_g = (const float*)d_in[3];
    const float* ln_b = (const float*)d_in[4];
    const float* wq   = (const float*)d_in[5];
    const float* bq   = (const float*)d_in[6];
    const float* wk   = (const float*)d_in[7];
    const float* bk   = (const float*)d_in[8];
    const float* wv   = (const float*)d_in[9];
    const float* bv   = (const float*)d_in[10];
    const float* wo   = (const float*)d_in[11];
    const float* bo   = (const float*)d_in[12];
    const float* rel  = (const float*)d_in[13];
    float* out = (float*)d_out;

    const size_t TSZ = (size_t)M_PAD * D_MODEL;     // 4,194,304 ushorts
    unsigned short* ws   = (unsigned short*)d_ws;
    unsigned short* qn   = ws;
    unsigned short* kn   = qn + TSZ;
    unsigned short* vn   = kn + TSZ;
    unsigned short* qh   = vn + TSZ;
    unsigned short* kh   = qh + TSZ;
    unsigned short* vt   = kh + TSZ;
    unsigned short* aout = vt + TSZ;
    unsigned short* wqb  = aout + TSZ;
    unsigned short* wkb  = wqb + 1024 * 1024;
    unsigned short* wvb  = wkb + 1024 * 1024;
    unsigned short* wob  = wvb + 1024 * 1024;
    unsigned short* relb = wob + 1024 * 1024;

    cvt_all<<<dim3(1024, 5), 256, 0, stream>>>(wq, wk, wv, wo, rel,
                                               wqb, wkb, wvb, wob, relb);

    ln_all<<<dim3(M_PAD, 3), 256, 0, stream>>>(q, k, v, ln_g, ln_b, qn, kn, vn);

    gemm_qkv<<<dim3(8, 32, 3), 256, 0, stream>>>(qn, kn, vn, wqb, wkb, wvb,
                                                 bq, bk, bv, qh, kh, vt);

    attn_mfma<<<512, 256, 0, stream>>>(qh, kh, vt, relb, aout);

    gemm_out<<<dim3(8, 32), 256, 0, stream>>>(aout, wob, bo, q, out);
}

// Round 13
// 181.468 us; speedup vs baseline: 1.3696x; 1.0858x over previous
//
#include <hip/hip_runtime.h>
#include <hip/hip_bf16.h>

#define D_MODEL 1024
#define N_HEAD  16
#define D_K     64
#define MAX_LEN 1000
#define B_      4
#define S_      1000
#define S_PAD   1024
#define M_PAD   (B_ * S_PAD)       // 4096
#define M_REAL  (B_ * S_)          // 4000
#define LN_EPS  1e-5f
#define SCALE_L2E 0.1803368801111204f   // 0.125 * log2(e)
#define REL_ROWS (2*MAX_LEN-1)     // 1999

typedef __attribute__((ext_vector_type(8))) short short8;
typedef __attribute__((ext_vector_type(4))) float f32x4;

__device__ __forceinline__ unsigned short f2b(float f) {
    unsigned u = __builtin_bit_cast(unsigned, f);
    u = (u + 0x7FFFu + ((u >> 16) & 1u)) >> 16;
    return (unsigned short)u;
}

__device__ __forceinline__ unsigned short f2b_trunc(float f) {
    return (unsigned short)(__builtin_bit_cast(unsigned, f) >> 16);
}

__device__ __forceinline__ float b2f(unsigned short u) {
    return __builtin_bit_cast(float, (unsigned)u << 16);
}

__device__ __forceinline__ f32x4 mfma16(short8 a, short8 b, f32x4 c) {
    return __builtin_amdgcn_mfma_f32_16x16x32_bf16(a, b, c, 0, 0, 0);
}

__device__ __forceinline__ void gload_lds16(const void* g, void* l) {
    __builtin_amdgcn_global_load_lds(
        (const __attribute__((address_space(1))) unsigned int*)g,
        (__attribute__((address_space(3))) unsigned int*)l, 16, 0, 0);
}

// ---------------- merged fp32 -> bf16 convert (5 tensors) ----------------
__global__ void cvt_all(const float* __restrict__ s0, const float* __restrict__ s1,
                        const float* __restrict__ s2, const float* __restrict__ s3,
                        const float* __restrict__ s4,
                        unsigned short* __restrict__ d0, unsigned short* __restrict__ d1,
                        unsigned short* __restrict__ d2, unsigned short* __restrict__ d3,
                        unsigned short* __restrict__ d4) {
    int y = blockIdx.y;
    const float* in; unsigned short* out; int n4;
    switch (y) {
        case 0: in = s0; out = d0; n4 = 262144; break;
        case 1: in = s1; out = d1; n4 = 262144; break;
        case 2: in = s2; out = d2; n4 = 262144; break;
        case 3: in = s3; out = d3; n4 = 262144; break;
        default: in = s4; out = d4; n4 = REL_ROWS * D_K / 4; break;
    }
    int i = blockIdx.x * blockDim.x + threadIdx.x;
    if (i >= n4) return;
    float4 v = ((const float4*)in)[i];
    ushort4 o;
    o.x = f2b(v.x); o.y = f2b(v.y); o.z = f2b(v.z); o.w = f2b(v.w);
    ((ushort4*)out)[i] = o;
}

// ---------------- merged LayerNorm x3 -> bf16, padded rows zeroed ----------------
__global__ void ln_all(const float* __restrict__ xq, const float* __restrict__ xk,
                       const float* __restrict__ xv, const float* __restrict__ g,
                       const float* __restrict__ beta,
                       unsigned short* __restrict__ yq, unsigned short* __restrict__ yk,
                       unsigned short* __restrict__ yv) {
    int which = blockIdx.y;
    const float* x = which == 0 ? xq : which == 1 ? xk : xv;
    unsigned short* y = which == 0 ? yq : which == 1 ? yk : yv;

    int r = blockIdx.x;            // padded row index
    int b = r >> 10, i = r & 1023;
    unsigned short* yr = y + (size_t)r * D_MODEL;
    int tid = threadIdx.x;
    if (i >= S_) {
#pragma unroll
        for (int l = 0; l < 4; ++l) yr[tid + l * 256] = 0;
        return;
    }
    const float* xr = x + ((size_t)b * S_ + i) * D_MODEL;
    float v[4];
    float s = 0.f, sq = 0.f;
#pragma unroll
    for (int l = 0; l < 4; ++l) {
        v[l] = xr[tid + l * 256];
        s += v[l];
        sq += v[l] * v[l];
    }
#pragma unroll
    for (int o = 32; o > 0; o >>= 1) {
        s += __shfl_down(s, o, 64);
        sq += __shfl_down(sq, o, 64);
    }
    __shared__ float rs[4], rq[4];
    if ((tid & 63) == 0) { rs[tid >> 6] = s; rq[tid >> 6] = sq; }
    __syncthreads();
    if (tid == 0) {
        rs[0] = rs[0] + rs[1] + rs[2] + rs[3];
        rq[0] = rq[0] + rq[1] + rq[2] + rq[3];
    }
    __syncthreads();
    float mu = rs[0] * (1.0f / D_MODEL);
    float var = rq[0] * (1.0f / D_MODEL) - mu * mu;
    float rstd = rsqrtf(var + LN_EPS);
#pragma unroll
    for (int l = 0; l < 4; ++l) {
        int c = tid + l * 256;
        yr[c] = f2b((v[l] - mu) * rstd * g[c] + beta[c]);
    }
}

// ---------------- GEMM core: double-buffered K-loop (T3 2-phase) ----------------
// As/Bs are [2][128*32] ushorts. stage(k+1) issued BEFORE compute(k); 1 barrier/step.
// MODE 0: head layout [b,h,i,d]; MODE 1: transposed head [b,h,d,i]; MODE 2: fp32 +resid
template<int MODE>
__device__ __forceinline__ void gemm_body(
        const unsigned short* __restrict__ X, const unsigned short* __restrict__ W,
        const float* __restrict__ bias, const float* __restrict__ resid,
        unsigned short* __restrict__ Yb, float* __restrict__ Yf,
        unsigned short* As, unsigned short* Bs, int row0, int col0) {
    int tid = threadIdx.x;
    int lane = tid & 63, w = tid >> 6;
    int wr = w >> 1, wc = w & 1;
    int fr = lane & 15, fk = (lane >> 4) * 8;

    f32x4 acc[4][4];
#pragma unroll
    for (int fm = 0; fm < 4; ++fm)
#pragma unroll
        for (int fn = 0; fn < 4; ++fn) acc[fm][fn] = (f32x4)0.f;

    int c0 = (w * 2 + 0) * 64 + lane;
    int c1 = (w * 2 + 1) * 64 + lane;
    const unsigned short* xs0 = X + (size_t)(row0 + (c0 >> 2)) * 1024 + (c0 & 3) * 8;
    const unsigned short* xs1 = X + (size_t)(row0 + (c1 >> 2)) * 1024 + (c1 & 3) * 8;
    const unsigned short* ws0 = W + (size_t)(col0 + (c0 >> 2)) * 1024 + (c0 & 3) * 8;
    const unsigned short* ws1 = W + (size_t)(col0 + (c1 >> 2)) * 1024 + (c1 & 3) * 8;
    int do0 = (w * 2 + 0) * 512;
    int do1 = (w * 2 + 1) * 512;

    auto stage = [&](int buf, int k0) {
        gload_lds16(xs0 + k0, As + buf * 4096 + do0);
        gload_lds16(xs1 + k0, As + buf * 4096 + do1);
        gload_lds16(ws0 + k0, Bs + buf * 4096 + do0);
        gload_lds16(ws1 + k0, Bs + buf * 4096 + do1);
    };

    stage(0, 0);

    for (int it = 0; it < 32; ++it) {
        __syncthreads();                        // tile `it` landed (drains own vmcnt)
        if (it < 31) stage((it & 1) ^ 1, (it + 1) * 32);   // prefetch next tile

        const unsigned short* Ab = As + (it & 1) * 4096;
        const unsigned short* Bb = Bs + (it & 1) * 4096;
        short8 a[4], b[4];
#pragma unroll
        for (int fm = 0; fm < 4; ++fm)
            a[fm] = *(const short8*)(Ab + (wr * 64 + fm * 16 + fr) * 32 + fk);
#pragma unroll
        for (int fn = 0; fn < 4; ++fn)
            b[fn] = *(const short8*)(Bb + (wc * 64 + fn * 16 + fr) * 32 + fk);
#pragma unroll
        for (int fm = 0; fm < 4; ++fm)
#pragma unroll
            for (int fn = 0; fn < 4; ++fn)
                acc[fm][fn] = mfma16(a[fm], b[fn], acc[fm][fn]);
    }

#pragma unroll
    for (int fm = 0; fm < 4; ++fm) {
#pragma unroll
        for (int fn = 0; fn < 4; ++fn) {
            int cg = col0 + wc * 64 + fn * 16 + fr;
            float bv = bias[cg];
#pragma unroll
            for (int r = 0; r < 4; ++r) {
                int rg = row0 + wr * 64 + fm * 16 + (lane >> 4) * 4 + r;
                float val = acc[fm][fn][r] + bv;
                int b_ = rg >> 10, i = rg & 1023;
                if (MODE == 0) {
                    int h = cg >> 6, d = cg & 63;
                    Yb[(((size_t)(b_ * N_HEAD + h)) * S_PAD + i) * D_K + d] = f2b(val);
                } else if (MODE == 1) {
                    int h = cg >> 6, d = cg & 63;
                    Yb[(((size_t)(b_ * N_HEAD + h)) * D_K + d) * S_PAD + i] = f2b(val);
                } else {
                    if (i < S_) {
                        size_t orow = (size_t)b_ * S_ + i;
                        Yf[orow * 1024 + cg] = val + resid[orow * 1024 + cg];
                    }
                }
            }
        }
    }
}

// merged Q/K/V projections: grid (8, 32, 3), XCD-chunked swizzle (768 = 8*96)
__global__ __launch_bounds__(256) void gemm_qkv(
        const unsigned short* __restrict__ qn, const unsigned short* __restrict__ kn,
        const unsigned short* __restrict__ vn,
        const unsigned short* __restrict__ wqb, const unsigned short* __restrict__ wkb,
        const unsigned short* __restrict__ wvb,
        const float* __restrict__ bq, const float* __restrict__ bk,
        const float* __restrict__ bv,
        unsigned short* __restrict__ qh, unsigned short* __restrict__ kh,
        unsigned short* __restrict__ vt) {
    __shared__ __align__(16) unsigned short As[2][128 * 32];
    __shared__ __align__(16) unsigned short Bs[2][128 * 32];
    int fid = blockIdx.x + (blockIdx.y << 3) + (blockIdx.z << 8);   // [0,768)
    int swz = (fid & 7) * 96 + (fid >> 3);                          // bijective
    int bz = swz >> 8;
    int rem = swz & 255;
    int row0 = (rem >> 3) * 128, col0 = (rem & 7) * 128;
    if (bz == 0)
        gemm_body<0>(qn, wqb, bq, nullptr, qh, nullptr, As[0], Bs[0], row0, col0);
    else if (bz == 1)
        gemm_body<0>(kn, wkb, bk, nullptr, kh, nullptr, As[0], Bs[0], row0, col0);
    else
        gemm_body<1>(vn, wvb, bv, nullptr, vt, nullptr, As[0], Bs[0], row0, col0);
}

// final output projection + residual: grid (8,32), XCD-chunked swizzle (256 = 8*32)
__global__ __launch_bounds__(256) void gemm_out(
        const unsigned short* __restrict__ X, const unsigned short* __restrict__ W,
        const float* __restrict__ bias, const float* __restrict__ resid,
        float* __restrict__ Yf) {
    __shared__ __align__(16) unsigned short As[2][128 * 32];
    __shared__ __align__(16) unsigned short Bs[2][128 * 32];
    int fid = blockIdx.x + (blockIdx.y << 3);       // [0,256)
    int swz = (fid & 7) * 32 + (fid >> 3);          // bijective
    int row0 = (swz >> 3) * 128, col0 = (swz & 7) * 128;
    gemm_body<2>(X, W, bias, resid, nullptr, Yf, As[0], Bs[0], row0, col0);
}

// ---------------- Flash attention: dbuf K/V, 2 slabs/wave, counted-vmcnt rel (r12) ----------------
#define QRW 84    // QR scratch stride (79 used)
#define PW  72    // P scratch stride (64 used), same buffer as QR
__device__ __forceinline__ void attn_slab(
        const unsigned short* __restrict__ Kc, const unsigned short* __restrict__ Vc,
        unsigned short* __restrict__ qp, const short8 (*rl)[2],
        short8 aq0, short8 aq1, f32x4* accO, float* mrun, float* lrun,
        bool mask_needed, int j0, int fr, int fk8, int rgrp, int rsw) {
    // ---- QK^T from LDS ----
    f32x4 accS[4];
#pragma unroll
    for (int fj = 0; fj < 4; ++fj) accS[fj] = (f32x4)0.f;
    __builtin_amdgcn_s_setprio(1);
#pragma unroll
    for (int fj = 0; fj < 4; ++fj) {
        int kb = (fj * 16 + fr) * 64 + fk8;
        accS[fj] = mfma16(aq0, *(const short8*)(Kc + (kb ^ rsw)), accS[fj]);
        accS[fj] = mfma16(aq1, *(const short8*)(Kc + ((kb + 32) ^ rsw)), accS[fj]);
    }
    // ---- Q @ relband^T; spill (truncated bf16) for diagonal gather ----
#pragma unroll
    for (int fu = 0; fu < 5; ++fu) {
        f32x4 qr = (f32x4)0.f;
        qr = mfma16(aq0, rl[fu][0], qr);
        qr = mfma16(aq1, rl[fu][1], qr);
#pragma unroll
        for (int r = 0; r < 4; ++r)
            qp[(rgrp + r) * QRW + fu * 16 + fr] = f2b_trunc(qr[r]);
    }
    __builtin_amdgcn_s_setprio(0);

    // ---- assemble scores (mask hoisted out of hot path) ----
    float sc[4][4];
#pragma unroll
    for (int fj = 0; fj < 4; ++fj) {
        int j_loc = fj * 16 + fr;
#pragma unroll
        for (int r = 0; r < 4; ++r) {
            int col = rgrp + r - j_loc + 63;   // in [0,78]
            sc[fj][r] = (accS[fj][r] + b2f(qp[(rgrp + r) * QRW + col])) * SCALE_L2E;
        }
    }
    if (mask_needed) {
#pragma unroll
        for (int fj = 0; fj < 4; ++fj) {
            int j_loc = fj * 16 + fr;
            if (j0 + j_loc >= S_) {
#pragma unroll
                for (int r = 0; r < 4; ++r) sc[fj][r] = -3e38f;
            }
        }
    }

    // ---- row max ----
    float pm[4];
#pragma unroll
    for (int r = 0; r < 4; ++r)
        pm[r] = fmaxf(fmaxf(sc[0][r], sc[1][r]), fmaxf(sc[2][r], sc[3][r]));
#pragma unroll
    for (int mask = 1; mask <= 8; mask <<= 1)
#pragma unroll
        for (int r = 0; r < 4; ++r)
            pm[r] = fmaxf(pm[r], __shfl_xor(pm[r], mask, 64));

    // ---- defer-max: rescale only when max grew by > 8 (log2 units) ----
    float dmax = fmaxf(fmaxf(pm[0] - mrun[0], pm[1] - mrun[1]),
                       fmaxf(pm[2] - mrun[2], pm[3] - mrun[3]));
    if (!__all(dmax <= 8.0f)) {
#pragma unroll
        for (int r = 0; r < 4; ++r) {
            float mn = fmaxf(mrun[r], pm[r]);
            float scl = __builtin_amdgcn_exp2f(mrun[r] - mn);
            mrun[r] = mn;
            lrun[r] *= scl;
#pragma unroll
            for (int fd = 0; fd < 4; ++fd) accO[fd][r] *= scl;
        }
    }

    // ---- exp (base-2) + truncated bf16 P store ----
    float rsum[4];
#pragma unroll
    for (int r = 0; r < 4; ++r) rsum[r] = 0.f;
#pragma unroll
    for (int fj = 0; fj < 4; ++fj) {
#pragma unroll
        for (int r = 0; r < 4; ++r) {
            float p = __builtin_amdgcn_exp2f(sc[fj][r] - mrun[r]);
            rsum[r] += p;
            qp[(rgrp + r) * PW + fj * 16 + fr] = f2b_trunc(p);
        }
    }
#pragma unroll
    for (int mask = 1; mask <= 8; mask <<= 1)
#pragma unroll
        for (int r = 0; r < 4; ++r)
            rsum[r] += __shfl_xor(rsum[r], mask, 64);
#pragma unroll
    for (int r = 0; r < 4; ++r) lrun[r] += rsum[r];

    // ---- PV from LDS ----
    short8 ap0 = *(const short8*)(qp + fr * PW + fk8);
    short8 ap1 = *(const short8*)(qp + fr * PW + 32 + fk8);
    __builtin_amdgcn_s_setprio(1);
#pragma unroll
    for (int fd = 0; fd < 4; ++fd) {
        int vb = (fd * 16 + fr) * 64 + fk8;
        accO[fd] = mfma16(ap0, *(const short8*)(Vc + (vb ^ rsw)), accO[fd]);
        accO[fd] = mfma16(ap1, *(const short8*)(Vc + ((vb + 32) ^ rsw)), accO[fd]);
    }
    __builtin_amdgcn_s_setprio(0);
}

__global__ __launch_bounds__(256, 2) void attn_mfma(
        const unsigned short* __restrict__ qh, const unsigned short* __restrict__ kh,
        const unsigned short* __restrict__ vt, const unsigned short* __restrict__ relb,
        unsigned short* __restrict__ aout) {
    __shared__ __align__(16) unsigned short Ks[2][64 * 64];   // 16 KB
    __shared__ __align__(16) unsigned short Vs[2][64 * 64];   // 16 KB
    __shared__ __align__(16) unsigned short QP[4][16 * QRW];  // 10.5 KB

    int tid = threadIdx.x, lane = tid & 63, w = tid >> 6;
    int bid = blockIdx.x;                      // 512 blocks
    int swz = (bid & 7) * 64 + (bid >> 3);     // XCD-chunked, bijective (512 = 8*64)
    int bh = swz >> 3;                         // uniform across block
    int i0a = (((swz & 7) * 8) + 2 * w) * 16;  // slab a; slab b = i0a + 16
    int fr = lane & 15, fk8 = (lane >> 4) * 8, rgrp = (lane >> 4) * 4;
    int rsw = (fr & 7) << 3;                   // read-side XOR (ushort units)

    const unsigned short* kbase = kh + (size_t)bh * S_PAD * D_K;   // [i][d]
    const unsigned short* vtbase = vt + (size_t)bh * D_K * S_PAD;  // [d][i]

    const unsigned short* qpa = qh + ((size_t)bh * S_PAD + i0a + fr) * D_K + fk8;
    short8 aqa0 = *(const short8*)(qpa);
    short8 aqa1 = *(const short8*)(qpa + 32);
    const unsigned short* qpb = qpa + 16 * D_K;
    short8 aqb0 = *(const short8*)(qpb);
    short8 aqb1 = *(const short8*)(qpb + 32);

    f32x4 accOa[4], accOb[4];
    float mruna[4], lruna[4], mrunb[4], lrunb[4];
#pragma unroll
    for (int fd = 0; fd < 4; ++fd) { accOa[fd] = (f32x4)0.f; accOb[fd] = (f32x4)0.f; }
#pragma unroll
    for (int r = 0; r < 4; ++r) {
        mruna[r] = -3e38f; lruna[r] = 0.f;
        mrunb[r] = -3e38f; lrunb[r] = 0.f;
    }

    unsigned short* qp = QP[w];
    int row_in = lane >> 3, slot = lane & 7;

    auto stage = [&](int buf, int it2) {
        int j0s = it2 * 64;
#pragma unroll
        for (int cc = 0; cc < 2; ++cc) {
            int c = w * 2 + cc;
            int r = c * 8 + row_in;
            gload_lds16(kbase + (size_t)(j0s + r) * 64 + (slot ^ row_in) * 8,
                        &Ks[buf][c * 512]);
        }
#pragma unroll
        for (int cc = 0; cc < 2; ++cc) {
            int c = w * 2 + cc;
            int d = c * 8 + row_in;
            gload_lds16(vtbase + (size_t)d * S_PAD + j0s + (slot ^ row_in) * 8,
                        &Vs[buf][c * 512]);
        }
    };

    stage(0, 0);
    __syncthreads();   // tile 0 landed

    for (int it = 0; it < 16; ++it) {
        int cur = it & 1, j0 = it * 64;
        bool mask_needed = (j0 + 63 >= S_);

        // ---- ALL rel fragments for BOTH slabs issued BEFORE stage ----
        short8 rl[6][2];
        int ub = i0a - j0 + (S_ - D_K);
#pragma unroll
        for (int fu = 0; fu < 6; ++fu) {
            int u = ub + fu * 16 + fr;
            u = u < 0 ? 0 : (u > REL_ROWS - 1 ? REL_ROWS - 1 : u);
            const unsigned short* rp = relb + (size_t)u * D_K + fk8;
            rl[fu][0] = *(const short8*)(rp);
            rl[fu][1] = *(const short8*)(rp + 32);
        }
        __builtin_amdgcn_sched_barrier(0);   // pin rel loads ahead of stage issue

        if (it < 15) stage(cur ^ 1, it + 1);  // prefetch next tile (other buffer)

        attn_slab(Ks[cur], Vs[cur], qp, rl, aqa0, aqa1, accOa, mruna, lruna,
                  mask_needed, j0, fr, fk8, rgrp, rsw);
        attn_slab(Ks[cur], Vs[cur], qp, rl + 1, aqb0, aqb1, accOb, mrunb, lrunb,
                  mask_needed, j0, fr, fk8, rgrp, rsw);

        __syncthreads();   // next tile landed; all waves done with Ks/Vs[cur]
    }

    // ---- normalize + store both slabs ----
    int b_ = bh >> 4, h = bh & 15;
#pragma unroll
    for (int r = 0; r < 4; ++r) {
        float inva = 1.0f / lruna[r];
        float invb = 1.0f / lrunb[r];
        int ma = b_ * S_PAD + i0a + rgrp + r;
        int mb = ma + 16;
#pragma unroll
        for (int fd = 0; fd < 4; ++fd) {
            int c = h * D_K + fd * 16 + fr;
            aout[(size_t)ma * D_MODEL + c] = f2b(accOa[fd][r] * inva);
            aout[(size_t)mb * D_MODEL + c] = f2b(accOb[fd][r] * invb);
        }
    }
}

extern "C" void kernel_launch(void* const* d_in, const int* in_sizes, int n_in,
                              void* d_out, int out_size, void* d_ws, size_t ws_size,
                              hipStream_t stream) {
    const float* q    = (const float*)d_in[0];
    const float* k    = (const float*)d_in[1];
    const float* v    = (const float*)d_in[2];
    const float* ln_g = (const float*)d_in[3];
    const float* ln_b = (const float*)d_in[4];
    const float* wq   = (const float*)d_in[5];
    const float* bq   = (const float*)d_in[6];
    const float* wk   = (const float*)d_in[7];
    const float* bk   = (const float*)d_in[8];
    const float* wv   = (const float*)d_in[9];
    const float* bv   = (const float*)d_in[10];
    const float* wo   = (const float*)d_in[11];
    const float* bo   = (const float*)d_in[12];
    const float* rel  = (const float*)d_in[13];
    float* out = (float*)d_out;

    const size_t TSZ = (size_t)M_PAD * D_MODEL;     // 4,194,304 ushorts
    unsigned short* ws   = (unsigned short*)d_ws;
    unsigned short* qn   = ws;
    unsigned short* kn   = qn + TSZ;
    unsigned short* vn   = kn + TSZ;
    unsigned short* qh   = vn + TSZ;
    unsigned short* kh   = qh + TSZ;
    unsigned short* vt   = kh + TSZ;
    unsigned short* aout = vt + TSZ;
    unsigned short* wqb  = aout + TSZ;
    unsigned short* wkb  = wqb + 1024 * 1024;
    unsigned short* wvb  = wkb + 1024 * 1024;
    unsigned short* wob  = wvb + 1024 * 1024;
    unsigned short* relb = wob + 1024 * 1024;

    cvt_all<<<dim3(1024, 5), 256, 0, stream>>>(wq, wk, wv, wo, rel,
                                               wqb, wkb, wvb, wob, relb);

    ln_all<<<dim3(M_PAD, 3), 256, 0, stream>>>(q, k, v, ln_g, ln_b, qn, kn, vn);

    gemm_qkv<<<dim3(8, 32, 3), 256, 0, stream>>>(qn, kn, vn, wqb, wkb, wvb,
                                                 bq, bk, bv, qh, kh, vt);

    attn_mfma<<<512, 256, 0, stream>>>(qh, kh, vt, relb, aout);

    gemm_out<<<dim3(8, 32), 256, 0, stream>>>(aout, wob, bo, q, out);
}